// Round 5
// baseline (296.128 us; speedup 1.0000x reference)
//
#include <hip/hip_runtime.h>
#include <hip/hip_bf16.h>
#include <stdint.h>

#define B_ROWS 16384
#define D_K    2048
#define C_COLS 1000
#define C_PAD  1024
#define EPS_D2 1e-12f

// GEMM geometry: 256x256 tile, BK=32, 8 waves (2M x 4N), 4-deep LDS ring,
// 32x32x16 MFMA (wave tile 128x64 = 4 mblk x 2 nblk).
#define BM 256
#define BN 256
#define BK 32
#define NT (D_K / BK)          // 64 K-tiles
#define BUF_BYTES 32768        // A 16K + B 16K per K-tile
#define NBUF 4                 // ring depth (128 KiB LDS total)

typedef __attribute__((ext_vector_type(8))) short bf16x8;
typedef __attribute__((ext_vector_type(16))) float f32x16;

__device__ __forceinline__ void async16(void* lds, const void* g) {
    __builtin_amdgcn_global_load_lds(
        (const __attribute__((address_space(1))) unsigned int*)g,
        (__attribute__((address_space(3))) unsigned int*)lds,
        16, 0, 0);
}

// 4 f32 -> 4 bf16 (RNE) packed into uint2
__device__ __forceinline__ uint2 pack_bf16x4(float4 v) {
    union { __hip_bfloat162 h; uint32_t u; } a, b;
    a.h = __float22bfloat162_rn(make_float2(v.x, v.y));
    b.h = __float22bfloat162_rn(make_float2(v.z, v.w));
    uint2 r; r.x = a.u; r.y = b.u; return r;
}

// Wave-per-row prep: fp32 -> bf16 (RNE) + fp32 sum-of-squares. (unchanged)
__global__ __launch_bounds__(256) void prep_all(
    const float* __restrict__ x, const float* __restrict__ w,
    __hip_bfloat16* __restrict__ xb, __hip_bfloat16* __restrict__ wb,
    float* __restrict__ x2, float* __restrict__ w2) {
    const int t = threadIdx.x;
    const int wave = t >> 6;
    const int lane = t & 63;
    const int row = blockIdx.x * 4 + wave;

    const float* src;
    uint4* dst;
    float* norm_out;
    bool valid;
    if (row < B_ROWS) {
        src = x + (size_t)row * D_K;
        dst = (uint4*)(xb + (size_t)row * D_K);
        norm_out = x2 + row;
        valid = true;
    } else {
        int c = row - B_ROWS;
        src = w + (size_t)c * D_K;
        dst = (uint4*)(wb + (size_t)c * D_K);
        norm_out = w2 + c;
        valid = (c < C_COLS);
    }

    float4 v[8];
    if (valid) {
        const float4* s4 = (const float4*)src;
        #pragma unroll
        for (int i = 0; i < 4; i++) {
            v[2 * i]     = s4[2 * lane + 128 * i];
            v[2 * i + 1] = s4[2 * lane + 1 + 128 * i];
        }
    } else {
        #pragma unroll
        for (int i = 0; i < 8; i++) v[i] = make_float4(0.f, 0.f, 0.f, 0.f);
    }

    float ss = 0.f;
    #pragma unroll
    for (int i = 0; i < 8; i++)
        ss += v[i].x * v[i].x + v[i].y * v[i].y + v[i].z * v[i].z + v[i].w * v[i].w;

    #pragma unroll
    for (int i = 0; i < 4; i++) {
        uint2 a = pack_bf16x4(v[2 * i]);
        uint2 b = pack_bf16x4(v[2 * i + 1]);
        uint4 p; p.x = a.x; p.y = a.y; p.z = b.x; p.w = b.y;
        dst[lane + 64 * i] = p;
    }

    #pragma unroll
    for (int off = 32; off > 0; off >>= 1) ss += __shfl_down(ss, off, 64);
    if (lane == 0 && valid) *norm_out = ss;
}

// 256x256 tile, BK=32, 512 threads = 8 waves (2Mx4N), wave tile 128x64.
// 32x32x16 MFMA: per wave per K-tile: 4mblk x 2nblk x 2kf = 16 MFMA,
// 12 ds_read_b128 frags. 4-deep LDS ring, distance-3 gload_lds prefetch,
// counted vmcnt(8) + ONE raw barrier per K-tile; NO lgkm fences in the loop
// (compiler's own waitcnt counting interleaves reads with MFMAs).
__global__ __launch_bounds__(512, 2) void dml_gemm(
    const __hip_bfloat16* __restrict__ A,   // [B_ROWS, D_K] bf16
    const __hip_bfloat16* __restrict__ Bm,  // [C_PAD, D_K] bf16 (padded)
    const float* __restrict__ x2, const float* __restrict__ w2,
    const float* __restrict__ scales, float* __restrict__ out)
{
    __shared__ __align__(16) char smem[NBUF * BUF_BYTES];   // 131072 B

    const int tid  = threadIdx.x;
    const int wave = tid >> 6;
    const int lane = tid & 63;
    const int wm = wave >> 2;     // 0..1
    const int wn = wave & 3;      // 0..3

    // XCD-chunked mapping: 256 blocks = 1/CU; XCD x owns m-tiles [8x, 8x+8) x all 4 n.
    const int id  = blockIdx.x;
    const int xcd = id & 7;
    const int j5  = id >> 3;
    const int m0  = (xcd * 8 + (j5 & 7)) * BM;
    const int n0  = (j5 >> 3) * BN;

    // ---- staging geometry: 1024 16B-chunks per operand per K-tile; 2 per thread.
    // chunk L: row r = L>>2, stored pos c = L&3 holds global k-chunk g = c ^ ((r>>1)&3)
    const int L0 = tid, L1 = tid + 512;
    const int r0 = L0 >> 2, g0 = (L0 & 3) ^ ((r0 >> 1) & 3);
    const int r1 = L1 >> 2, g1 = (L1 & 3) ^ ((r1 >> 1) & 3);
    const __hip_bfloat16* pA0 = A  + (size_t)(m0 + r0) * D_K + g0 * 8;
    const __hip_bfloat16* pA1 = A  + (size_t)(m0 + r1) * D_K + g1 * 8;
    const __hip_bfloat16* pB0 = Bm + (size_t)(n0 + r0) * D_K + g0 * 8;
    const __hip_bfloat16* pB1 = Bm + (size_t)(n0 + r1) * D_K + g1 * 8;
    char* ldA0 = smem + L0 * 16;
    char* ldA1 = smem + L1 * 16;
    char* ldB0 = smem + 16384 + L0 * 16;
    char* ldB1 = smem + 16384 + L1 * 16;

    // ---- fragment read ptrs (32x32x16): A row = wm*128 + mb*32 + (lane&31),
    // k-chunk c = kf*2 + (lane>>5), stored at pos c ^ ((row>>1)&3).
    // Swizzle term depends only on lane&31 (mb*32, wm*128 are ≡0 mod 8).
    const int l31 = lane & 31;
    const int l5  = lane >> 5;
    const int rsw = (l31 >> 1) & 3;
    const char* fA = smem + (wm * 128 + l31) * 64;           // + buf + mb*2048 + ofs[kf]
    const char* fB = smem + 16384 + (wn * 64 + l31) * 64;    // + buf + nb*2048 + ofs[kf]
    const int ofs0 = ((0 * 2 + l5) ^ rsw) * 16;              // kf=0 chunk byte offset
    const int ofs1 = ((1 * 2 + l5) ^ rsw) * 16;              // kf=1 chunk byte offset

    f32x16 acc[4][2] = {};

    // ---- prologue: stage K-tiles 0..2 (12 loads/thread), retire tile 0.
    #pragma unroll
    for (int tgt = 0; tgt < 3; ++tgt) {
        const int sbo = tgt * BUF_BYTES;
        async16(ldA0 + sbo, pA0 + tgt * BK);
        async16(ldA1 + sbo, pA1 + tgt * BK);
        async16(ldB0 + sbo, pB0 + tgt * BK);
        async16(ldB1 + sbo, pB1 + tgt * BK);
    }
    asm volatile("s_waitcnt vmcnt(8)" ::: "memory");
    __builtin_amdgcn_s_barrier();
    __builtin_amdgcn_sched_barrier(0);

    // ---- main loop: tile t reads buf[t&3], stages tile t+3 into buf[(t+3)&3].
    #pragma unroll 1
    for (int t = 0; t < NT; ++t) {
        const int bo  = (t & 3) * BUF_BYTES;
        const int tgt = t + 3;
        const int sbo = (tgt & 3) * BUF_BYTES;

        // stage first (earliest issue; lands >=2 tiles from now)
        if (tgt < NT) {
            async16(ldA0 + sbo, pA0 + tgt * BK);
            async16(ldA1 + sbo, pA1 + tgt * BK);
            async16(ldB0 + sbo, pB0 + tgt * BK);
            async16(ldB1 + sbo, pB1 + tgt * BK);
        }

        bf16x8 a[4], b[2];
        // ---- kf = 0 ----
        b[0] = *(const bf16x8*)(fB + bo + 0 * 2048 + ofs0);
        b[1] = *(const bf16x8*)(fB + bo + 1 * 2048 + ofs0);
        #pragma unroll
        for (int mb = 0; mb < 4; ++mb) a[mb] = *(const bf16x8*)(fA + bo + mb * 2048 + ofs0);
        __builtin_amdgcn_s_setprio(1);
        #pragma unroll
        for (int mb = 0; mb < 4; ++mb)
            #pragma unroll
            for (int nb = 0; nb < 2; ++nb)
                acc[mb][nb] = __builtin_amdgcn_mfma_f32_32x32x16_bf16(a[mb], b[nb], acc[mb][nb], 0, 0, 0);
        __builtin_amdgcn_s_setprio(0);

        // ---- kf = 1 ----
        b[0] = *(const bf16x8*)(fB + bo + 0 * 2048 + ofs1);
        b[1] = *(const bf16x8*)(fB + bo + 1 * 2048 + ofs1);
        #pragma unroll
        for (int mb = 0; mb < 4; ++mb) a[mb] = *(const bf16x8*)(fA + bo + mb * 2048 + ofs1);
        __builtin_amdgcn_s_setprio(1);
        #pragma unroll
        for (int mb = 0; mb < 4; ++mb)
            #pragma unroll
            for (int nb = 0; nb < 2; ++nb)
                acc[mb][nb] = __builtin_amdgcn_mfma_f32_32x32x16_bf16(a[mb], b[nb], acc[mb][nb], 0, 0, 0);
        __builtin_amdgcn_s_setprio(0);

        // checkpoint: retire next tile's staging (counted, never 0 until tail).
        if (t < NT - 3)       asm volatile("s_waitcnt vmcnt(8)" ::: "memory");
        else if (t == NT - 3) asm volatile("s_waitcnt vmcnt(4)" ::: "memory");
        else if (t == NT - 2) asm volatile("s_waitcnt vmcnt(0)" ::: "memory");
        if (t < NT - 1) {
            __builtin_amdgcn_s_barrier();
            __builtin_amdgcn_sched_barrier(0);
        }
    }

    // ---- epilogue: -s*sqrt(max(x2+w2-2*acc, eps)); direct stores.
    // 32x32 C/D layout: col = lane&31, row = (reg&3) + 8*(reg>>2) + 4*(lane>>5).
    const float s = scales[0];
    const int colb = n0 + wn * 64 + l31;
    const int rowb = m0 + wm * 128 + l5 * 4;

    #pragma unroll
    for (int mb = 0; mb < 4; ++mb) {
        #pragma unroll
        for (int nb = 0; nb < 2; ++nb) {
            const int col = colb + nb * 32;
            if (col < C_COLS) {
                const float w2v = w2[col];
                #pragma unroll
                for (int r = 0; r < 16; ++r) {
                    const int row = rowb + mb * 32 + (r & 3) + 8 * (r >> 2);
                    float d2 = x2[row] + w2v - 2.0f * acc[mb][nb][r];
                    d2 = fmaxf(d2, EPS_D2);
                    out[(size_t)row * C_COLS + col] = -s * __builtin_sqrtf(d2);
                }
            }
        }
    }
}

extern "C" void kernel_launch(void* const* d_in, const int* in_sizes, int n_in,
                              void* d_out, int out_size, void* d_ws, size_t ws_size,
                              hipStream_t stream) {
    const float* x      = (const float*)d_in[0];
    const float* w      = (const float*)d_in[1];
    const float* scales = (const float*)d_in[2];
    float* out = (float*)d_out;

    char* ws = (char*)d_ws;
    __hip_bfloat16* xb = (__hip_bfloat16*)ws;                                  // 67,108,864 B
    __hip_bfloat16* wb = (__hip_bfloat16*)(ws + (size_t)B_ROWS * D_K * 2);     //  4,194,304 B
    float* x2 = (float*)(ws + (size_t)B_ROWS * D_K * 2 + (size_t)C_PAD * D_K * 2);
    float* w2 = x2 + B_ROWS;

    prep_all<<<dim3((B_ROWS + C_PAD) / 4), dim3(256), 0, stream>>>(x, w, xb, wb, x2, w2);
    dml_gemm<<<dim3((B_ROWS / BM) * (C_PAD / BN)), dim3(512), 0, stream>>>(xb, wb, x2, w2, scales, out);
}